// Round 1
// baseline (103.617 us; speedup 1.0000x reference)
//
#include <hip/hip_runtime.h>

#define HW_ (1024 * 1024)

typedef _Float16 half8 __attribute__((ext_vector_type(8)));
typedef __fp16 fp16x2 __attribute__((ext_vector_type(2)));
typedef float f32x16 __attribute__((ext_vector_type(16)));
typedef unsigned int uint;

// ---------------------------------------------------------------------------
// R12 = R11 with build_filter_table FUSED into the main kernel.
// Theory: dur_us = 2x43us harness ws-poison fills (256MiB each, not ours)
//         + ~11us main (at its 67MB HBM floor) + ~4us table kernel + node.
// The 4KB filter table depended only on (lane, po) with compile-time tap
// positions, so each lane now reconstructs its four A-fragments directly
// from the 400-float filter arrays: constexpr TAPS[po][kk] folds the
// mapping, leaving ~25 predicated L1/L2-hit scalar loads + ~60 VALU per
// thread, issued BEFORE __syncthreads so they hide under the global->LDS
// staging latency (kernel is BW-bound; VALU/issue slots are idle there).
// d_ws is no longer used; kernel_launch is a single graph node.
// ---------------------------------------------------------------------------

// tap offset dy*5+dx into a 5x5 filter, or -1 for structural zero.
// TAPS[po][kk]; derived from R11's tap_from_kk (verified value-by-value).
__device__ constexpr short TAPS[2][32] = {
    //  kk: 0..15 = taps (2h + j>>2, pb + (j&3)); 16,17 = row4 pb+{0,1};
    //  18,19,20 = col sdx rows 0,1,2; 24,25 = row4 pb+2+{0,1};
    //  26 = (3,sdx); 27 = (4,sdx); 21-23,28-31 = zero.
    { 0, 1, 2, 3, 5, 6, 7, 8, 10, 11, 12, 13, 15, 16, 17, 18,
      20, 21, 4, 9, 14, -1, -1, -1, 22, 23, 19, 24, -1, -1, -1, -1 },
    { 1, 2, 3, 4, 6, 7, 8, 9, 11, 12, 13, 14, 16, 17, 18, 19,
      21, 22, 0, 5, 10, -1, -1, -1, 23, 24, 15, 20, -1, -1, -1, -1 },
};

template <int PO, int KK0>
__device__ __forceinline__ half8 build_frag(const float* __restrict__ fb,
                                            int off25) {
    half8 r;
#pragma unroll
    for (int j = 0; j < 8; ++j) {
        const int to = TAPS[PO][KK0 + j];   // constant-folds after unroll
        r[j] = (to >= 0) ? (_Float16)fb[off25 + to] : (_Float16)0.f;
    }
    return r;
}

__global__ __launch_bounds__(256, 2)
void demosaick_fused(const float* __restrict__ mosaick,
                     const float* __restrict__ sel_filts,
                     const float* __restrict__ green_filts,
                     float* __restrict__ out) {
    // [0,1360): image tile 20 rows x 68 cols fp16; [1360,1392): zero pad
    __shared__ __align__(16) _Float16 smem[1392];

    const int tid = threadIdx.x;
    const int b   = blockIdx.z;
    const int by0 = blockIdx.y * 16, bx0 = blockIdx.x * 64;
    const float* img = mosaick + (size_t)b * HW_;

    const bool interior = (blockIdx.x != 0) & (blockIdx.x != gridDim.x - 1) &
                          (blockIdx.y != 0) & (blockIdx.y != gridDim.y - 1);
    if (interior) {
        // 680 dwords; dword index == idx; rows of 34 float2.
        uint* smw_w = (uint*)smem;
        for (int idx = tid; idx < 680; idx += 256) {
            int row = idx / 34, c2 = idx - row * 34;
            float2 v = *(const float2*)(img + (size_t)(by0 - 2 + row) * 1024
                                            + (bx0 - 2 + 2 * c2));
            union { fp16x2 h; uint u; } cv;
            cv.h = __builtin_amdgcn_cvt_pkrtz(v.x, v.y);
            smw_w[idx] = cv.u;
        }
    } else {
        for (int idx = tid; idx < 1360; idx += 256) {
            int row = idx / 68, col = idx - row * 68;
            int gy = by0 - 2 + row; gy = gy < 0 ? 0 : (gy > 1023 ? 1023 : gy);
            int gx = bx0 - 2 + col; gx = gx < 0 ? 0 : (gx > 1023 ? 1023 : gx);
            smem[idx] = (_Float16)img[gy * 1024 + gx];
        }
    }
    if (tid < 32) smem[1360 + tid] = (_Float16)0.f;

    // ---- A-fragment reconstruction (replaces the precomputed table) ----
    // Issued before the barrier: its ~25 L1/L2-hit loads overlap the
    // staging loads above. Layout identical to R11's tbl:
    //   a0 = row m=n, kk = 8h..8h+7;  a1 = kk = 16+8h..16+8h+7;  po = 0/1.
    const int lane = tid & 63, w = tid >> 6;
    const int n = lane & 31, h = lane >> 5;   // n: A-row / pixel col
    const float* fb = (n & 1) ? green_filts : sel_filts;
    const int off25 = (2 * (n >> 3) + ((n & 3) >> 1)) * 25;

    half8 a0p0, a1p0, a0p1, a1p1;
    if (h == 0) {
        a0p0 = build_frag<0, 0>(fb, off25);
        a1p0 = build_frag<0, 16>(fb, off25);
        a0p1 = build_frag<1, 0>(fb, off25);
        a1p1 = build_frag<1, 16>(fb, off25);
    } else {
        a0p0 = build_frag<0, 8>(fb, off25);
        a1p0 = build_frag<0, 24>(fb, off25);
        a0p1 = build_frag<1, 8>(fb, off25);
        a1p1 = build_frag<1, 24>(fb, off25);
    }

    __syncthreads();

    const uint* smw = (const uint*)smem;
    const unsigned short* sms = (const unsigned short*)smem;
    float* outp = out + (size_t)b * HW_;
    const float L2E = 1.44269504f;

    // ---- Stage 1: ALL B-fragment gathers (independent, overlap latency) ----
    uint B0[4][4], B1[4][4];
    #pragma unroll
    for (int u = 0; u < 4; ++u) {
        const int r  = 4 * w + u;                 // tile row of computed px
        const int po = (u & 1) ^ 1;               // y=by0+r even -> po=1
        const int pb = po, sdx = po ? 0 : 4;
        const int e0 = (r + 2 * h) * 68 + 2 * n + po;
        const int e4 = (r + 4) * 68 + 2 * n + po;
        const int rs0 = h ? 3 : 0, rs1 = h ? 4 : 1;

        B0[u][0] = smw[(e0 + pb) >> 1];
        B0[u][1] = smw[(e0 + pb + 2) >> 1];
        B0[u][2] = smw[(e0 + 68 + pb) >> 1];
        B0[u][3] = smw[(e0 + 68 + pb + 2) >> 1];
        B1[u][0] = smw[(e4 + pb + 2 * h) >> 1];
        uint us0 = sms[(r + rs0) * 68 + 2 * n + po + sdx];
        uint us1 = sms[(r + rs1) * 68 + 2 * n + po + sdx];
        B1[u][1] = us0 | (us1 << 16);
        B1[u][2] = sms[h ? 1360 : ((r + 2) * 68 + 2 * n + po + sdx)];
        B1[u][3] = 0;
    }

    // ---- Stage 2: MFMA + softmax epilogue per group ----
    #pragma unroll
    for (int u = 0; u < 4; ++u) {
        const int r  = 4 * w + u;
        const int po = (u & 1) ^ 1;

        union { uint u4[4]; half8 v; } b0c = {{B0[u][0], B0[u][1], B0[u][2], B0[u][3]}};
        union { uint u4[4]; half8 v; } b1c = {{B1[u][0], B1[u][1], B1[u][2], B1[u][3]}};

        f32x16 acc = {};
        acc = __builtin_amdgcn_mfma_f32_32x32x16_f16(po ? a0p1 : a0p0, b0c.v, acc, 0, 0, 0);
        acc = __builtin_amdgcn_mfma_f32_32x32x16_f16(po ? a1p1 : a1p0, b1c.v, acc, 0, 0, 0);

        // Channel-duplicated A: even regs = sel, odd regs = green (all 8 pairs).
        float se = 0.f, eg = 0.f;
        #pragma unroll
        for (int rr = 0; rr < 16; rr += 2) {
            float e = __builtin_amdgcn_exp2f(acc[rr] * L2E);
            se += e;
            eg = fmaf(e, acc[rr + 1], eg);
        }
        float gh = eg * __builtin_amdgcn_rcpf(se);

        if (h == 1) {
            // pass-through tap lives in this lane's B0 fragment (row r+2):
            // po=1 -> b0[0] (col 2n+2); po=0 -> b0[3] (col 2n+3)
            float pass = (float)(po ? b0c.v[0] : b0c.v[3]);
            float2 o;
            if (po) { o.x = pass; o.y = gh; }     // y even: (pass, comp)
            else    { o.x = gh;   o.y = pass; }   // y odd:  (comp, pass)
            *(float2*)(outp + (size_t)(by0 + r) * 1024 + bx0 + 2 * n) = o;
        }
    }
}

extern "C" void kernel_launch(void* const* d_in, const int* in_sizes, int n_in,
                              void* d_out, int out_size, void* d_ws, size_t ws_size,
                              hipStream_t stream) {
    const float* mosaick     = (const float*)d_in[0];
    const float* sel_filts   = (const float*)d_in[1];
    const float* green_filts = (const float*)d_in[2];
    float* out = (float*)d_out;
    const int B = in_sizes[0] / HW_;          // 8
    dim3 grid(1024 / 64, 1024 / 16, B);       // (16, 64, 8) = 8192 blocks
    dim3 block(256, 1, 1);
    hipLaunchKernelGGL(demosaick_fused, grid, block, 0, stream,
                       mosaick, sel_filts, green_filts, out);
}